// Round 1
// baseline (97.689 us; speedup 1.0000x reference)
//
#include <hip/hip_runtime.h>

// ---------------------------------------------------------------------------
// Conv2dfft == 3x3 SAME cross-correlation conv (pad=1) + bias.
// N=32, C=128, F=128, H=W=32.  Implicit-GEMM, bf16 MFMA 16x16x32.
// Round 9: prepass converts x fp32->bf16 ONCE into a pre-padded, pre-swizzled
// LDS-image layout (halo rows/cols zeroed, stride-40 bank layout baked in).
// conv_main staging is now pure global_load_lds DMA (3x16B per thread per
// chunk): no in-loop f2bf, no ds_write, no predication, no halo zeroing.
// K-loop structure otherwise = R8: af weight fragments double-buffered
// global->VGPR, x double-buffered in LDS, 512 blocks x 256 thr, 2 blocks/CU.
// ---------------------------------------------------------------------------

typedef short bf16x8 __attribute__((ext_vector_type(8)));   // 8 bf16 (4 VGPR)
typedef short bf16x4 __attribute__((ext_vector_type(4)));   // 4 bf16 (2 VGPR)
typedef float f32x4  __attribute__((ext_vector_type(4)));   // MFMA 16x16 acc

__device__ __forceinline__ short f2bf(float f) {            // RNE fp32->bf16
  unsigned u = __builtin_bit_cast(unsigned, f);
  u = (u + 0x7fffu + ((u >> 16) & 1u)) >> 16;
  return (short)u;
}

// global -> LDS async DMA, 16B per lane. LDS dest = wave-uniform base +
// lane*16 (HW-applied); global src is per-lane.
__device__ __forceinline__ void gload_lds16(const void* g, void* l) {
  using gptr_t = const __attribute__((address_space(1))) unsigned int*;
  using lptr_t = __attribute__((address_space(3))) unsigned int*;
  __builtin_amdgcn_global_load_lds((gptr_t)(unsigned long long)g,
                                   (lptr_t)(unsigned int)(unsigned long long)l,
                                   16, 0, 0);
}

// ---------------------------------------------------------------------------
// Layout of xp (bf16, in workspace after bc2):
//   xp[(n*4 + chunk)*34 + xr][ROWIMG=1536 shorts]
// where xr = h+1 (h in -1..32), row image = col(0..33)*40 + c(0..31), pads
// ([c 32..39] and shorts [1360..1535]) are never read. Rows xr..xr+3 of one
// chunk-plane are contiguous: a block's chunk tile = 4*3072 = 12288 B.
// ---------------------------------------------------------------------------

// ---------------------------------------------------------------------------
// Merged prepass.
// Blocks [0, 4352):  x -> xp   (one block per (n, chunk, xr))
// Blocks [4352, 4928): weight (F,C,3,3) fp32 -> bc2 fragment-major:
//   bc2[chunk(4)*9+tap][fblk(8)][lane(64)][j(8)]
// ---------------------------------------------------------------------------
__global__ __launch_bounds__(256) void conv_prep(const float* __restrict__ x,
                                                 const float* __restrict__ w,
                                                 short* __restrict__ bc2,
                                                 short* __restrict__ xp) {
  const int b = blockIdx.x;
  const int t = threadIdx.x;
  if (b >= 4352) {                       // ---- weight prep (576 blocks) ----
    int tid = (b - 4352) * 256 + t;      // [0, 147456)
    float v = w[tid];                    // coalesced
    int f   = tid / 1152;                // w layout: f*1152 + c*9 + tap
    int rem = tid - f * 1152;
    int c   = rem / 9;
    int tap = rem - c * 9;
    int dst = ((((c >> 5) * 9 + tap) * 8 + (f >> 4)) * 512)
            + (((c >> 3) & 3) * 16 + (f & 15)) * 8
            + (c & 7);
    bc2[dst] = f2bf(v);
    return;
  }
  // ---- x prep: one block per row-image ----
  const int xr = b % 34;                 // padded row index (h = xr-1)
  const int nc = b / 34;                 // n*4 + chunk
  const int n = nc >> 2, chunk = nc & 3;
  short* row = xp + (size_t)b * 1536;
  if (t < 16) {                          // zero halo cols 0 and 33
    bf16x4 z = {0, 0, 0, 0};
    *(bf16x4*)&row[((t >> 3) ? 33 : 0) * 40 + (t & 7) * 4] = z;
  }
  const int h  = xr - 1;
  const int w_ = t & 31;                 // coalesced over x's W dim
  const int g  = t >> 5;                 // channel group [0,8)
  bf16x4 v = {0, 0, 0, 0};
  if ((unsigned)h < 32u) {               // halo rows stay zero
    const float* src = x + (((size_t)(n * 128 + chunk * 32 + g * 4)) << 10)
                         + h * 32 + w_;
    v[0] = f2bf(src[0]);
    v[1] = f2bf(src[1024]);
    v[2] = f2bf(src[2048]);
    v[3] = f2bf(src[3072]);
  }
  *(bf16x4*)&row[(w_ + 1) * 40 + g * 4] = v;
}

// load one weight group (chunk,p): 12 coalesced global_load_dwordx4 from L2.
__device__ __forceinline__ void load_af(bf16x8* dst, const short* __restrict__ bc2,
                                        int chunk, int p, int fsel, int lane) {
  const short* base = bc2 + (((chunk * 9 + p * 3) * 8 + fsel * 4) * 512) + lane * 8;
#pragma unroll
  for (int q = 0; q < 3; ++q)
#pragma unroll
    for (int mt = 0; mt < 4; ++mt)
      dst[q * 4 + mt] = *(const bf16x8*)(base + (q * 8 + mt) * 512);
}

// ---------------------------------------------------------------------------
// Main: 512 blocks (2/CU) x 256 threads (4 waves).
// Block = image n_img, output rows h0..h0+1, 32 cols, 128 f.
// Wave: fsel=wv&1 (f-half), s_row=wv>>1 (one row); 4x2 acc of 16x16 tiles.
// Staging = 3 x global_load_lds(16B) per thread per chunk, issued at chunk
// top so HBM/L3 latency hides under the 72 MFMAs of the current chunk.
// ---------------------------------------------------------------------------
__global__ __launch_bounds__(256, 2) void conv_main(
    const short* __restrict__ xp, const short* __restrict__ bc2,
    const float* __restrict__ bias, float* __restrict__ out) {
  // xs[buf][r(4)][col(34)][c(32)] with col stride 40 shorts (80 B) baked into
  // xp: bf16x8 reads are 16-B aligned ds_read_b128, 2 lanes/bank (free).
  __shared__ __align__(16) short xs[2][6144];               // 24,576 B

  const int t    = threadIdx.x;
  const int lane = t & 63;
  const int wv   = t >> 6;
  const int n_img = blockIdx.x >> 4;
  const int h0    = (blockIdx.x & 15) << 1;

  const int l15  = lane & 15;
  const int quad = lane >> 4;
  const int fsel  = wv & 1;
  const int f_off = fsel * 64;
  const int s_row = wv >> 1;      // this wave's output row within the strip

  const int go = wv * 1024 + lane * 16;   // per-lane global offset (bytes)
  const int lo = wv * 1024;               // wave-uniform LDS offset (bytes)

  // af double-buffer: group = chunk*3+p, 12 frags (48 VGPRs) each.
  bf16x8 afA[12], afB[12];
  load_af(afA, bc2, 0, 0, fsel, lane);   // group 0 in flight ASAP

  // ---- stage chunk 0 tile (rows xr=h0..h0+3, contiguous 12288 B) ----
  {
    const char* src = (const char*)(xp + ((size_t)(n_img * 4 + 0) * 34 + h0) * 1536);
    char* dst = (char*)&xs[0][0];
#pragma unroll
    for (int rnd = 0; rnd < 3; ++rnd)
      gload_lds16(src + rnd * 4096 + go, dst + rnd * 4096 + lo);
  }

  f32x4 acc[4][2] = {};           // [mt(f)][nt(col-half)]
  __syncthreads();                // vmcnt(0) drain: chunk-0 stage complete

#pragma unroll
  for (int chunk = 0; chunk < 4; ++chunk) {
    // ---- issue next chunk's DMA stage first (oldest in vm queue) ----
    if (chunk < 3) {
      const char* src =
          (const char*)(xp + ((size_t)(n_img * 4 + chunk + 1) * 34 + h0) * 1536);
      char* dst = (char*)&xs[(chunk + 1) & 1][0];
#pragma unroll
      for (int rnd = 0; rnd < 3; ++rnd)
        gload_lds16(src + rnd * 4096 + go, dst + rnd * 4096 + lo);
    }
    const short* xbuf = xs[chunk & 1];
#pragma unroll
    for (int p = 0; p < 3; ++p) {
      const int grp = chunk * 3 + p;
      const bf16x8* cur = (grp & 1) ? afB : afA;
      bf16x8*       nxt = (grp & 1) ? afA : afB;
      if (grp < 11)
        load_af(nxt, bc2, (grp + 1) / 3, (grp + 1) % 3, fsel, lane);
#pragma unroll
      for (int q = 0; q < 3; ++q) {
        bf16x8 bfr[2];
#pragma unroll
        for (int nt = 0; nt < 2; ++nt) {
          int r   = s_row + p;
          int col = nt * 16 + l15 + q;
          bfr[nt] = *(const bf16x8*)&xbuf[r * 1536 + col * 40 + quad * 8];
        }
#pragma unroll
        for (int mt = 0; mt < 4; ++mt)
#pragma unroll
          for (int nt = 0; nt < 2; ++nt)
            acc[mt][nt] = __builtin_amdgcn_mfma_f32_16x16x32_bf16(
                cur[q * 4 + mt], bfr[nt], acc[mt][nt], 0, 0, 0);
      }
    }
    // barrier: my chunk's reads done; next chunk's stage (issued above,
    // oldest) is drained by __syncthreads' vmcnt(0).
    if (chunk < 3) __syncthreads();
  }

  // ---- epilogue: C/D layout col=lane&15 (w), row=quad*4+reg (f) ----
  const int h = h0 + s_row;
#pragma unroll
  for (int nt = 0; nt < 2; ++nt) {
    int w_out = nt * 16 + l15;
#pragma unroll
    for (int mt = 0; mt < 4; ++mt) {
#pragma unroll
      for (int reg = 0; reg < 4; ++reg) {
        int f = f_off + mt * 16 + quad * 4 + reg;
        out[(((size_t)n_img * 128 + f) * 32 + h) * 32 + w_out] =
            acc[mt][nt][reg] + bias[f];
      }
    }
  }
}

// ---------------------------------------------------------------------------
extern "C" void kernel_launch(void* const* d_in, const int* in_sizes, int n_in,
                              void* d_out, int out_size, void* d_ws, size_t ws_size,
                              hipStream_t stream) {
  const float* x    = (const float*)d_in[0];   // 32*128*32*32
  const float* w    = (const float*)d_in[1];   // 128*128*3*3
  const float* bias = (const float*)d_in[2];   // 128
  float* out = (float*)d_out;                  // 32*128*32*32
  short* bc2 = (short*)d_ws;                   // 294,912 B fragment-major weights
  short* xp  = bc2 + 147456;                   // 13,369,344 B pre-padded bf16 x

  conv_prep<<<4928, 256, 0, stream>>>(x, w, bc2, xp);
  conv_main<<<512, 256, 0, stream>>>(xp, bc2, bias, out);
}

// Round 2
// 92.440 us; speedup vs baseline: 1.0568x; 1.0568x over previous
//
#include <hip/hip_runtime.h>

// ---------------------------------------------------------------------------
// Conv2dfft == 3x3 SAME cross-correlation conv (pad=1) + bias.
// N=32, C=128, F=128, H=W=32.  Implicit-GEMM, bf16 MFMA 16x16x32.
// Round 10: occupancy push. R9's xp prepass REVERTED (cost ~10us, bought 0).
// Strip = 1 output row: 1024 blocks x 256 thr, 3 blocks/CU via
// __launch_bounds__(256,3) -> 12 waves/CU (was 8). Wave = fsel(2) x
// col-half(2): 64f x 16 cols x 1 row, acc 4x1 (16 VGPR), xv 12, af 96
// -> ~155 VGPR, fits the 170 cap of 3 waves/SIMD without spilling.
// K-loop structure = R8 (best so far): x reg-prefetch -> LDS double buffer
// per 32-c chunk, af weight fragments double-buffered global->VGPR,
// scalar-store epilogue. Accumulation order identical to R8 (bit-exact).
// ---------------------------------------------------------------------------

typedef short bf16x8 __attribute__((ext_vector_type(8)));   // 8 bf16 (4 VGPR)
typedef short bf16x4 __attribute__((ext_vector_type(4)));   // 4 bf16 (2 VGPR)
typedef float f32x4  __attribute__((ext_vector_type(4)));   // MFMA 16x16 acc

__device__ __forceinline__ short f2bf(float f) {            // RNE fp32->bf16
  unsigned u = __builtin_bit_cast(unsigned, f);
  u = (u + 0x7fffu + ((u >> 16) & 1u)) >> 16;
  return (short)u;
}

// ---------------------------------------------------------------------------
// Prepass: weight (F,C,3,3) fp32 -> bf16 fragment-major:
//   bc2[chunk(4)*9+tap][fblk(8)][lane(64)][j(8)]
// A-frag elem j of lane (quad*16+l15) = W[f=fblk*16+l15][c=chunk*32+quad*8+j].
// ---------------------------------------------------------------------------
__global__ __launch_bounds__(256) void conv_wprep(const float* __restrict__ w,
                                                  short* __restrict__ bc2) {
  int tid = blockIdx.x * 256 + threadIdx.x;    // [0, 147456)
  float v = w[tid];                            // coalesced
  int f   = tid / 1152;                        // w layout: f*1152 + c*9 + tap
  int rem = tid - f * 1152;
  int c   = rem / 9;
  int tap = rem - c * 9;
  int dst = ((((c >> 5) * 9 + tap) * 8 + (f >> 4)) * 512)
          + (((c >> 3) & 3) * 16 + (f & 15)) * 8
          + (c & 7);
  bc2[dst] = f2bf(v);
}

// load one weight group (chunk,p): 12 coalesced global_load_dwordx4 from L2.
__device__ __forceinline__ void load_af(bf16x8* dst, const short* __restrict__ bc2,
                                        int chunk, int p, int fsel, int lane) {
  const short* base = bc2 + (((chunk * 9 + p * 3) * 8 + fsel * 4) * 512) + lane * 8;
#pragma unroll
  for (int q = 0; q < 3; ++q)
#pragma unroll
    for (int mt = 0; mt < 4; ++mt)
      dst[q * 4 + mt] = *(const bf16x8*)(base + (q * 8 + mt) * 512);
}

// ---------------------------------------------------------------------------
// Main: 1024 blocks (3/CU) x 256 threads (4 waves).
// Block = image n_img, output row h0, 32 cols, 128 f.
// Wave: fsel=wv&1 (f-half), chalf=wv>>1 (col-half); 4x1 acc of 16x16 tiles.
// ---------------------------------------------------------------------------
__global__ __launch_bounds__(256, 3) void conv_main(
    const float* __restrict__ x, const short* __restrict__ bc2,
    const float* __restrict__ bias, float* __restrict__ out) {
  // xs[buf][row(3)][col(34)][c(32 + 8 pad)] ; stride 40 shorts = 80 B:
  // bf16x8 reads 16-B aligned (ds_read_b128).
  __shared__ __align__(16) short xs[2][3 * 34 * 40];      // 16,320 B

  const int t    = threadIdx.x;
  const int lane = t & 63;
  const int wv   = t >> 6;
  const int n_img = blockIdx.x >> 5;
  const int h0    = blockIdx.x & 31;

  const int l15  = lane & 15;
  const int quad = lane >> 4;
  const int fsel  = wv & 1;
  const int f_off = fsel * 64;
  const int chalf = wv >> 1;      // this wave's 16-col half

  const int w_ = t & 31;          // staged output col (coalesced)
  const int g  = t >> 5;          // staging group [0,8)
  const float* xb = x + n_img * 128 * 1024;

  // af double-buffer: group = chunk*3+p, 12 frags (48 VGPRs) each.
  bf16x8 afA[12], afB[12];
  load_af(afA, bc2, 0, 0, fsel, lane);   // group 0 in flight ASAP

  // Zero halo cols (col 0 == w=-1, col 33 == w=32) in BOTH buffers, once.
  // 2 buf x 3 r x 2 col x 8 int2 = 96 threads.
  if (t < 96) {
    int buf = t / 48, rem = t % 48;
    int r = rem >> 4, rem2 = rem & 15;
    int colsel = rem2 >> 3, q4 = rem2 & 7;
    *(int2*)&xs[buf][(r * 34 + colsel * 33) * 40 + q4 * 4] = make_int2(0, 0);
  }

  f32x4 acc[4] = {};              // [mt(f)] ; nt fixed = chalf
  float xv[12];

  // ---- chunk 0 x -> regs -> buf 0 : rows h0-1..h0+1, 32 c ----
#pragma unroll
  for (int i = 0; i < 3; ++i) {
    int idx = i * 8 + g;          // [0,24) = r*8 + cq
    int r = idx >> 3, cq = idx & 7;
    int hr = h0 - 1 + r;
    bool ok = (unsigned)hr < 32u;
#pragma unroll
    for (int cc = 0; cc < 4; ++cc)
      xv[i * 4 + cc] = ok ? xb[(cq * 4 + cc) * 1024 + hr * 32 + w_] : 0.f;
  }
#pragma unroll
  for (int i = 0; i < 3; ++i) {
    int idx = i * 8 + g;
    int r = idx >> 3, cq = idx & 7;
    bf16x4 v = { f2bf(xv[i*4+0]), f2bf(xv[i*4+1]), f2bf(xv[i*4+2]), f2bf(xv[i*4+3]) };
    *(bf16x4*)&xs[0][(r * 34 + w_ + 1) * 40 + cq * 4] = v;
  }
  __syncthreads();

#pragma unroll
  for (int chunk = 0; chunk < 4; ++chunk) {
    // ---- prefetch next chunk's x into regs (hides under 36 MFMAs) ----
    if (chunk < 3) {
#pragma unroll
      for (int i = 0; i < 3; ++i) {
        int idx = i * 8 + g;
        int r = idx >> 3, cq = idx & 7;
        int hr = h0 - 1 + r;
        bool ok = (unsigned)hr < 32u;
#pragma unroll
        for (int cc = 0; cc < 4; ++cc)
          xv[i * 4 + cc] =
              ok ? xb[((chunk + 1) * 32 + cq * 4 + cc) * 1024 + hr * 32 + w_] : 0.f;
      }
    }
    const short* xbuf = xs[chunk & 1];
#pragma unroll
    for (int p = 0; p < 3; ++p) {
      const int grp = chunk * 3 + p;
      const bf16x8* cur = (grp & 1) ? afB : afA;
      bf16x8*       nxt = (grp & 1) ? afA : afB;
      if (grp < 11)
        load_af(nxt, bc2, (grp + 1) / 3, (grp + 1) % 3, fsel, lane);
#pragma unroll
      for (int q = 0; q < 3; ++q) {
        int col = chalf * 16 + l15 + q;
        bf16x8 bfr = *(const bf16x8*)&xbuf[(p * 34 + col) * 40 + quad * 8];
#pragma unroll
        for (int mt = 0; mt < 4; ++mt)
          acc[mt] = __builtin_amdgcn_mfma_f32_16x16x32_bf16(
              cur[q * 4 + mt], bfr, acc[mt], 0, 0, 0);
      }
    }
    // ---- stage prefetched x into the other buffer ----
    if (chunk < 3) {
#pragma unroll
      for (int i = 0; i < 3; ++i) {
        int idx = i * 8 + g;
        int r = idx >> 3, cq = idx & 7;
        bf16x4 v = { f2bf(xv[i*4+0]), f2bf(xv[i*4+1]), f2bf(xv[i*4+2]), f2bf(xv[i*4+3]) };
        *(bf16x4*)&xs[(chunk + 1) & 1][(r * 34 + w_ + 1) * 40 + cq * 4] = v;
      }
      __syncthreads();
    }
  }

  // ---- epilogue: C/D layout col=lane&15 (w), row=quad*4+reg (f) ----
  const int w_out = chalf * 16 + l15;
#pragma unroll
  for (int mt = 0; mt < 4; ++mt) {
#pragma unroll
    for (int reg = 0; reg < 4; ++reg) {
      int f = f_off + mt * 16 + quad * 4 + reg;
      out[(((size_t)n_img * 128 + f) * 32 + h0) * 32 + w_out] =
          acc[mt][reg] + bias[f];
    }
  }
}

// ---------------------------------------------------------------------------
extern "C" void kernel_launch(void* const* d_in, const int* in_sizes, int n_in,
                              void* d_out, int out_size, void* d_ws, size_t ws_size,
                              hipStream_t stream) {
  const float* x    = (const float*)d_in[0];   // 32*128*32*32
  const float* w    = (const float*)d_in[1];   // 128*128*3*3
  const float* bias = (const float*)d_in[2];   // 128
  float* out = (float*)d_out;                  // 32*128*32*32
  short* bc2 = (short*)d_ws;                   // 294,912 B fragment-major weights

  conv_wprep<<<576, 256, 0, stream>>>(w, bc2);
  conv_main<<<1024, 256, 0, stream>>>(x, bc2, bias, out);
}

// Round 3
// 84.024 us; speedup vs baseline: 1.1626x; 1.1002x over previous
//
#include <hip/hip_runtime.h>

// ---------------------------------------------------------------------------
// Conv2dfft == 3x3 SAME cross-correlation conv (pad=1) + bias.
// N=32, C=128, F=128, H=W=32.  Implicit-GEMM, bf16 MFMA 16x16x32.
// Round 11: LDS-shared weights. Geometry = R8/R0 (best, 87.2us): 512 blocks
// x 256 thr, 2 blocks/CU, 2-row strip, wave = fsel(2) x s_row(2), acc 4x2.
// Change: af weight fragments are no longer loaded per-wave from L2 (2x
// redundant, 302 MB grid-wide, ~200-400cyc dependent chain per phase).
// Each group (24,576 B, contiguous in bc2) is DMA'd ONCE per block into a
// double-buffered LDS region via global_load_lds(16B) and ds_read_b128 by
// all 4 waves. Weight traffic halves; af latency becomes LDS-class.
// Barriers: per-phase (12/block) for the af buffer swap.
// Accumulation order identical to R0 (bit-exact absmax).
// ---------------------------------------------------------------------------

typedef short bf16x8 __attribute__((ext_vector_type(8)));   // 8 bf16 (4 VGPR)
typedef short bf16x4 __attribute__((ext_vector_type(4)));   // 4 bf16 (2 VGPR)
typedef float f32x4  __attribute__((ext_vector_type(4)));   // MFMA 16x16 acc

__device__ __forceinline__ short f2bf(float f) {            // RNE fp32->bf16
  unsigned u = __builtin_bit_cast(unsigned, f);
  u = (u + 0x7fffu + ((u >> 16) & 1u)) >> 16;
  return (short)u;
}

// global -> LDS async DMA, 16B per lane. LDS dest = wave-uniform base +
// lane*16 (HW-applied); global src is per-lane.
__device__ __forceinline__ void gload_lds16(const void* g, void* l) {
  using gptr_t = const __attribute__((address_space(1))) unsigned int*;
  using lptr_t = __attribute__((address_space(3))) unsigned int*;
  __builtin_amdgcn_global_load_lds((gptr_t)(unsigned long long)g,
                                   (lptr_t)(unsigned int)(unsigned long long)l,
                                   16, 0, 0);
}

// ---------------------------------------------------------------------------
// Prepass: weight (F,C,3,3) fp32 -> bf16 fragment-major:
//   bc2[chunk(4)*9+tap][fblk(8)][lane(64)][j(8)]
// A-frag elem j of lane (quad*16+l15) = W[f=fblk*16+l15][c=chunk*32+quad*8+j].
// Group (chunk,p) = taps p*3..p*3+2 -> bytes [g*24576, (g+1)*24576), g=chunk*3+p.
// ---------------------------------------------------------------------------
__global__ __launch_bounds__(256) void conv_wprep(const float* __restrict__ w,
                                                  short* __restrict__ bc2) {
  int tid = blockIdx.x * 256 + threadIdx.x;    // [0, 147456)
  float v = w[tid];                            // coalesced
  int f   = tid / 1152;                        // w layout: f*1152 + c*9 + tap
  int rem = tid - f * 1152;
  int c   = rem / 9;
  int tap = rem - c * 9;
  int dst = ((((c >> 5) * 9 + tap) * 8 + (f >> 4)) * 512)
          + (((c >> 3) & 3) * 16 + (f & 15)) * 8
          + (c & 7);
  bc2[dst] = f2bf(v);
}

// ---------------------------------------------------------------------------
// Main: 512 blocks (2/CU) x 256 threads (4 waves).
// Block = image n_img, output rows h0..h0+1, 32 cols, 128 f.
// Wave: fsel=wv&1 (f-half), s_row=wv>>1 (row); 4x2 acc of 16x16 tiles.
// ---------------------------------------------------------------------------
__global__ __launch_bounds__(256, 2) void conv_main(
    const float* __restrict__ x, const short* __restrict__ bc2,
    const float* __restrict__ bias, float* __restrict__ out) {
  // xs[buf][row(4)][col(34)][c(32 + 8 pad)] ; stride 40 shorts = 80 B.
  __shared__ __align__(16) short xs[2][4 * 34 * 40];      // 21,760 B
  // afl[buf][tap(3)][fblk(8)][lane(64)][8 shorts] = 24,576 B per buffer.
  __shared__ __align__(16) short afl[2][12288];           // 49,152 B

  const int t    = threadIdx.x;
  const int lane = t & 63;
  const int wv   = t >> 6;
  const int n_img = blockIdx.x >> 4;
  const int h0    = (blockIdx.x & 15) << 1;

  const int l15  = lane & 15;
  const int quad = lane >> 4;
  const int fsel  = wv & 1;
  const int f_off = fsel * 64;
  const int s_row = wv >> 1;      // this wave's output row within the strip

  const int w_ = t & 31;          // staged output col (coalesced)
  const int g  = t >> 5;          // staging group [0,8)
  const float* xb = x + n_img * 128 * 1024;

  // Per-lane global src base for af DMA (bc2 is already [group][1536 lanes*16B]).
  const char* bc2b = (const char*)bc2 + t * 16;

  // ---- stage af group 0 (6 x 16B DMA per thread, whole block = 24,576 B) ----
  {
    char* dst = (char*)&afl[0][0] + wv * 1024;   // wave-uniform; HW adds lane*16
#pragma unroll
    for (int r = 0; r < 6; ++r)
      gload_lds16(bc2b + r * 4096, dst + r * 4096);
  }

  // Zero halo cols (col 0 == w=-1, col 33 == w=32) in BOTH buffers, once.
  if (t < 128) {
    int buf = t >> 6, rem = t & 63;      // 2 buf x 4 r x 2 col x 8 int2
    int r = rem >> 4, rem2 = rem & 15;
    int colsel = rem2 >> 3, q4 = rem2 & 7;
    *(int2*)&xs[buf][(r * 34 + colsel * 33) * 40 + q4 * 4] = make_int2(0, 0);
  }

  f32x4 acc[4][2] = {};           // [mt(f)][nt(col-half)]
  float xv[16];

  // ---- chunk 0 x -> regs -> buf 0 : rows h0-1..h0+2, 32 c ----
#pragma unroll
  for (int i = 0; i < 4; ++i) {
    int idx = i * 8 + g;          // [0,32) = r*8 + cq
    int r = idx >> 3, cq = idx & 7;
    int hr = h0 - 1 + r;
    bool ok = (unsigned)hr < 32u;
#pragma unroll
    for (int cc = 0; cc < 4; ++cc)
      xv[i * 4 + cc] = ok ? xb[(cq * 4 + cc) * 1024 + hr * 32 + w_] : 0.f;
  }
#pragma unroll
  for (int i = 0; i < 4; ++i) {
    int idx = i * 8 + g;
    int r = idx >> 3, cq = idx & 7;
    bf16x4 v = { f2bf(xv[i*4+0]), f2bf(xv[i*4+1]), f2bf(xv[i*4+2]), f2bf(xv[i*4+3]) };
    *(bf16x4*)&xs[0][(r * 34 + w_ + 1) * 40 + cq * 4] = v;
  }
  __syncthreads();                // drains af group-0 DMA + x writes

#pragma unroll
  for (int chunk = 0; chunk < 4; ++chunk) {
#pragma unroll
    for (int p = 0; p < 3; ++p) {
      const int grp = chunk * 3 + p;
      // ---- issue next group's af DMA (drained by this phase's barrier) ----
      if (grp < 11) {
        const char* src = bc2b + (grp + 1) * 24576;
        char* dst = (char*)&afl[(grp + 1) & 1][0] + wv * 1024;
#pragma unroll
        for (int r = 0; r < 6; ++r)
          gload_lds16(src + r * 4096, dst + r * 4096);
      }
      // ---- issue next chunk's x loads (consumed at p==2 ds_write) ----
      if (p == 0 && chunk < 3) {
#pragma unroll
        for (int i = 0; i < 4; ++i) {
          int idx = i * 8 + g;
          int r = idx >> 3, cq = idx & 7;
          int hr = h0 - 1 + r;
          bool ok = (unsigned)hr < 32u;
#pragma unroll
          for (int cc = 0; cc < 4; ++cc)
            xv[i * 4 + cc] =
                ok ? xb[((chunk + 1) * 32 + cq * 4 + cc) * 1024 + hr * 32 + w_] : 0.f;
        }
      }
      // ---- compute phase: af from LDS, x from LDS, 24 MFMA ----
      const short* xbuf = xs[chunk & 1];
      const short* afb  = afl[grp & 1];
      bf16x8 af[12];
#pragma unroll
      for (int q = 0; q < 3; ++q)
#pragma unroll
        for (int mt = 0; mt < 4; ++mt)
          af[q * 4 + mt] =
              *(const bf16x8*)&afb[(q * 8 + fsel * 4 + mt) * 512 + lane * 8];
#pragma unroll
      for (int q = 0; q < 3; ++q) {
        bf16x8 bfr[2];
#pragma unroll
        for (int nt = 0; nt < 2; ++nt) {
          int r   = s_row + p;
          int col = nt * 16 + l15 + q;
          bfr[nt] = *(const bf16x8*)&xbuf[(r * 34 + col) * 40 + quad * 8];
        }
#pragma unroll
        for (int mt = 0; mt < 4; ++mt)
#pragma unroll
          for (int nt = 0; nt < 2; ++nt)
            acc[mt][nt] = __builtin_amdgcn_mfma_f32_16x16x32_bf16(
                af[q * 4 + mt], bfr[nt], acc[mt][nt], 0, 0, 0);
      }
      // ---- stage prefetched x into the other buffer ----
      if (p == 2 && chunk < 3) {
#pragma unroll
        for (int i = 0; i < 4; ++i) {
          int idx = i * 8 + g;
          int r = idx >> 3, cq = idx & 7;
          bf16x4 v = { f2bf(xv[i*4+0]), f2bf(xv[i*4+1]), f2bf(xv[i*4+2]), f2bf(xv[i*4+3]) };
          *(bf16x4*)&xs[(chunk + 1) & 1][(r * 34 + w_ + 1) * 40 + cq * 4] = v;
        }
      }
      if (grp < 11) __syncthreads();   // af buffer swap + DMA drain
    }
  }

  // ---- epilogue: C/D layout col=lane&15 (w), row=quad*4+reg (f) ----
  const int h = h0 + s_row;
#pragma unroll
  for (int nt = 0; nt < 2; ++nt) {
    int w_out = nt * 16 + l15;
#pragma unroll
    for (int mt = 0; mt < 4; ++mt) {
#pragma unroll
      for (int reg = 0; reg < 4; ++reg) {
        int f = f_off + mt * 16 + quad * 4 + reg;
        out[(((size_t)n_img * 128 + f) * 32 + h) * 32 + w_out] =
            acc[mt][nt][reg] + bias[f];
      }
    }
  }
}

// ---------------------------------------------------------------------------
extern "C" void kernel_launch(void* const* d_in, const int* in_sizes, int n_in,
                              void* d_out, int out_size, void* d_ws, size_t ws_size,
                              hipStream_t stream) {
  const float* x    = (const float*)d_in[0];   // 32*128*32*32
  const float* w    = (const float*)d_in[1];   // 128*128*3*3
  const float* bias = (const float*)d_in[2];   // 128
  float* out = (float*)d_out;                  // 32*128*32*32
  short* bc2 = (short*)d_ws;                   // 294,912 B fragment-major weights

  conv_wprep<<<576, 256, 0, stream>>>(w, bc2);
  conv_main<<<512, 256, 0, stream>>>(x, bc2, bias, out);
}

// Round 4
// 83.982 us; speedup vs baseline: 1.1632x; 1.0005x over previous
//
#include <hip/hip_runtime.h>

// ---------------------------------------------------------------------------
// Conv2dfft == 3x3 SAME cross-correlation conv (pad=1) + bias.
// N=32, C=128, F=128, H=W=32.  Implicit-GEMM, bf16 MFMA 16x16x32.
// Round 12: T4 counted-vmcnt pipeline. Structure = R11 (84.0us best): 512
// blocks x 256 thr, 2 blocks/CU, LDS-shared double-buffered af weights via
// global_load_lds, x reg-prefetch -> LDS double buffer.
// Change: the 11 in-loop __syncthreads() (each a full vmcnt(0) drain) become
// phase-top {s_waitcnt vmcnt(W) lgkmcnt(0); s_barrier} with counted W:
//   W=16 at phases 2,5,8 (the 16 x-prefetch loads ride through the barrier;
//   only the 6 af-DMA loads -- oldest in queue -- are forced complete),
//   W=0 elsewhere (queue holds only the 1-phase-old af DMA: near-free).
// x-prefetch issue moved p0 -> p1 (1.7-phase ride to its p2 consumer).
// MFMA cluster wrapped in s_setprio(1)/(0) (T5: 2 independent blocks/CU).
// Accumulation order identical to R11 (bit-exact absmax 0.03125).
// ---------------------------------------------------------------------------

typedef short bf16x8 __attribute__((ext_vector_type(8)));   // 8 bf16 (4 VGPR)
typedef short bf16x4 __attribute__((ext_vector_type(4)));   // 4 bf16 (2 VGPR)
typedef float f32x4  __attribute__((ext_vector_type(4)));   // MFMA 16x16 acc

__device__ __forceinline__ short f2bf(float f) {            // RNE fp32->bf16
  unsigned u = __builtin_bit_cast(unsigned, f);
  u = (u + 0x7fffu + ((u >> 16) & 1u)) >> 16;
  return (short)u;
}

// global -> LDS async DMA, 16B per lane. LDS dest = wave-uniform base +
// lane*16 (HW-applied); global src is per-lane.
__device__ __forceinline__ void gload_lds16(const void* g, void* l) {
  using gptr_t = const __attribute__((address_space(1))) unsigned int*;
  using lptr_t = __attribute__((address_space(3))) unsigned int*;
  __builtin_amdgcn_global_load_lds((gptr_t)(unsigned long long)g,
                                   (lptr_t)(unsigned int)(unsigned long long)l,
                                   16, 0, 0);
}

// ---------------------------------------------------------------------------
// Prepass: weight (F,C,3,3) fp32 -> bf16 fragment-major:
//   bc2[chunk(4)*9+tap][fblk(8)][lane(64)][j(8)]
// A-frag elem j of lane (quad*16+l15) = W[f=fblk*16+l15][c=chunk*32+quad*8+j].
// Group (chunk,p) = taps p*3..p*3+2 -> bytes [g*24576, (g+1)*24576), g=chunk*3+p.
// ---------------------------------------------------------------------------
__global__ __launch_bounds__(256) void conv_wprep(const float* __restrict__ w,
                                                  short* __restrict__ bc2) {
  int tid = blockIdx.x * 256 + threadIdx.x;    // [0, 147456)
  float v = w[tid];                            // coalesced
  int f   = tid / 1152;                        // w layout: f*1152 + c*9 + tap
  int rem = tid - f * 1152;
  int c   = rem / 9;
  int tap = rem - c * 9;
  int dst = ((((c >> 5) * 9 + tap) * 8 + (f >> 4)) * 512)
          + (((c >> 3) & 3) * 16 + (f & 15)) * 8
          + (c & 7);
  bc2[dst] = f2bf(v);
}

// ---------------------------------------------------------------------------
// Main: 512 blocks (2/CU) x 256 threads (4 waves).
// Block = image n_img, output rows h0..h0+1, 32 cols, 128 f.
// Wave: fsel=wv&1 (f-half), s_row=wv>>1 (row); 4x2 acc of 16x16 tiles.
// ---------------------------------------------------------------------------
__global__ __launch_bounds__(256, 2) void conv_main(
    const float* __restrict__ x, const short* __restrict__ bc2,
    const float* __restrict__ bias, float* __restrict__ out) {
  // xs[buf][row(4)][col(34)][c(32 + 8 pad)] ; stride 40 shorts = 80 B.
  __shared__ __align__(16) short xs[2][4 * 34 * 40];      // 21,760 B
  // afl[buf][tap(3)][fblk(8)][lane(64)][8 shorts] = 24,576 B per buffer.
  __shared__ __align__(16) short afl[2][12288];           // 49,152 B

  const int t    = threadIdx.x;
  const int lane = t & 63;
  const int wv   = t >> 6;
  const int n_img = blockIdx.x >> 4;
  const int h0    = (blockIdx.x & 15) << 1;

  const int l15  = lane & 15;
  const int quad = lane >> 4;
  const int fsel  = wv & 1;
  const int f_off = fsel * 64;
  const int s_row = wv >> 1;      // this wave's output row within the strip

  const int w_ = t & 31;          // staged output col (coalesced)
  const int g  = t >> 5;          // staging group [0,8)
  const float* xb = x + n_img * 128 * 1024;

  // Per-lane global src base for af DMA (bc2 is [group][1536 lanes*16B]).
  const char* bc2b = (const char*)bc2 + t * 16;

  // ---- stage af group 0 (6 x 16B DMA per thread, whole block = 24,576 B) ----
  {
    char* dst = (char*)&afl[0][0] + wv * 1024;   // wave-uniform; HW adds lane*16
#pragma unroll
    for (int r = 0; r < 6; ++r)
      gload_lds16(bc2b + r * 4096, dst + r * 4096);
  }

  // Zero halo cols (col 0 == w=-1, col 33 == w=32) in BOTH buffers, once.
  if (t < 128) {
    int buf = t >> 6, rem = t & 63;      // 2 buf x 4 r x 2 col x 8 int2
    int r = rem >> 4, rem2 = rem & 15;
    int colsel = rem2 >> 3, q4 = rem2 & 7;
    *(int2*)&xs[buf][(r * 34 + colsel * 33) * 40 + q4 * 4] = make_int2(0, 0);
  }

  f32x4 acc[4][2] = {};           // [mt(f)][nt(col-half)]
  float xv[16];

  // ---- chunk 0 x -> regs -> buf 0 : rows h0-1..h0+2, 32 c ----
#pragma unroll
  for (int i = 0; i < 4; ++i) {
    int idx = i * 8 + g;          // [0,32) = r*8 + cq
    int r = idx >> 3, cq = idx & 7;
    int hr = h0 - 1 + r;
    bool ok = (unsigned)hr < 32u;
#pragma unroll
    for (int cc = 0; cc < 4; ++cc)
      xv[i * 4 + cc] = ok ? xb[(cq * 4 + cc) * 1024 + hr * 32 + w_] : 0.f;
  }
#pragma unroll
  for (int i = 0; i < 4; ++i) {
    int idx = i * 8 + g;
    int r = idx >> 3, cq = idx & 7;
    bf16x4 v = { f2bf(xv[i*4+0]), f2bf(xv[i*4+1]), f2bf(xv[i*4+2]), f2bf(xv[i*4+3]) };
    *(bf16x4*)&xs[0][(r * 34 + w_ + 1) * 40 + cq * 4] = v;
  }
  __syncthreads();                // prologue barrier: af grp-0 DMA + x0 staged

#pragma unroll
  for (int chunk = 0; chunk < 4; ++chunk) {
#pragma unroll
    for (int p = 0; p < 3; ++p) {
      const int grp = chunk * 3 + p;
      // ---- phase-top barrier with counted vmcnt (T4) ----
      if (grp > 0) {
        __builtin_amdgcn_sched_barrier(0);
        if (grp == 2 || grp == 5 || grp == 8) {
          // queue: [af DMA(grp) x6 oldest, x-prefetch x16] -> complete the 6
          // DMAs, let the 16 x loads ride through the barrier.
          asm volatile("s_waitcnt vmcnt(16) lgkmcnt(0)" ::: "memory");
        } else {
          // queue holds only the 1-phase-old af DMA: near-free drain.
          asm volatile("s_waitcnt vmcnt(0) lgkmcnt(0)" ::: "memory");
        }
        __builtin_amdgcn_s_barrier();
        __builtin_amdgcn_sched_barrier(0);
      }
      // ---- issue next group's af DMA (completes at NEXT phase-top wait) ----
      if (grp < 11) {
        const char* src = bc2b + (grp + 1) * 24576;
        char* dst = (char*)&afl[(grp + 1) & 1][0] + wv * 1024;
#pragma unroll
        for (int r = 0; r < 6; ++r)
          gload_lds16(src + r * 4096, dst + r * 4096);
      }
      // ---- issue next chunk's x loads at p==1 (consumed at p==2 ds_write;
      //      rides the p==2 phase-top barrier via vmcnt(16)) ----
      if (p == 1 && chunk < 3) {
#pragma unroll
        for (int i = 0; i < 4; ++i) {
          int idx = i * 8 + g;
          int r = idx >> 3, cq = idx & 7;
          int hr = h0 - 1 + r;
          bool ok = (unsigned)hr < 32u;
#pragma unroll
          for (int cc = 0; cc < 4; ++cc)
            xv[i * 4 + cc] =
                ok ? xb[((chunk + 1) * 32 + cq * 4 + cc) * 1024 + hr * 32 + w_] : 0.f;
        }
      }
      // ---- compute phase: af from LDS, x from LDS, 24 MFMA ----
      const short* xbuf = xs[chunk & 1];
      const short* afb  = afl[grp & 1];
      bf16x8 af[12];
#pragma unroll
      for (int q = 0; q < 3; ++q)
#pragma unroll
        for (int mt = 0; mt < 4; ++mt)
          af[q * 4 + mt] =
              *(const bf16x8*)&afb[(q * 8 + fsel * 4 + mt) * 512 + lane * 8];
      __builtin_amdgcn_s_setprio(1);
#pragma unroll
      for (int q = 0; q < 3; ++q) {
        bf16x8 bfr[2];
#pragma unroll
        for (int nt = 0; nt < 2; ++nt) {
          int r   = s_row + p;
          int col = nt * 16 + l15 + q;
          bfr[nt] = *(const bf16x8*)&xbuf[(r * 34 + col) * 40 + quad * 8];
        }
#pragma unroll
        for (int mt = 0; mt < 4; ++mt)
#pragma unroll
          for (int nt = 0; nt < 2; ++nt)
            acc[mt][nt] = __builtin_amdgcn_mfma_f32_16x16x32_bf16(
                af[q * 4 + mt], bfr[nt], acc[mt][nt], 0, 0, 0);
      }
      __builtin_amdgcn_s_setprio(0);
      // ---- stage prefetched x into the other buffer (p==2) ----
      if (p == 2 && chunk < 3) {
#pragma unroll
        for (int i = 0; i < 4; ++i) {
          int idx = i * 8 + g;
          int r = idx >> 3, cq = idx & 7;
          bf16x4 v = { f2bf(xv[i*4+0]), f2bf(xv[i*4+1]), f2bf(xv[i*4+2]), f2bf(xv[i*4+3]) };
          *(bf16x4*)&xs[(chunk + 1) & 1][(r * 34 + w_ + 1) * 40 + cq * 4] = v;
        }
      }
    }
  }

  // ---- epilogue: C/D layout col=lane&15 (w), row=quad*4+reg (f) ----
  const int h = h0 + s_row;
#pragma unroll
  for (int nt = 0; nt < 2; ++nt) {
    int w_out = nt * 16 + l15;
#pragma unroll
    for (int mt = 0; mt < 4; ++mt) {
#pragma unroll
      for (int reg = 0; reg < 4; ++reg) {
        int f = f_off + mt * 16 + quad * 4 + reg;
        out[(((size_t)n_img * 128 + f) * 32 + h) * 32 + w_out] =
            acc[mt][nt][reg] + bias[f];
      }
    }
  }
}

// ---------------------------------------------------------------------------
extern "C" void kernel_launch(void* const* d_in, const int* in_sizes, int n_in,
                              void* d_out, int out_size, void* d_ws, size_t ws_size,
                              hipStream_t stream) {
  const float* x    = (const float*)d_in[0];   // 32*128*32*32
  const float* w    = (const float*)d_in[1];   // 128*128*3*3
  const float* bias = (const float*)d_in[2];   // 128
  float* out = (float*)d_out;                  // 32*128*32*32
  short* bc2 = (short*)d_ws;                   // 294,912 B fragment-major weights

  conv_wprep<<<576, 256, 0, stream>>>(w, bc2);
  conv_main<<<512, 256, 0, stream>>>(x, bc2, bias, out);
}